// Round 1
// baseline (679.759 us; speedup 1.0000x reference)
//
#include <hip/hip_runtime.h>
#include <hip/hip_bf16.h>
#include <math.h>

// Problem constants (fixed by the reference)
#define E_N 800000
#define C_N 64
#define H_N 4
#define D_N 16
#define NODES 50000

typedef __bf16 bf16x8 __attribute__((ext_vector_type(8)));
typedef float f32x4 __attribute__((ext_vector_type(4)));
typedef int i32x4 __attribute__((ext_vector_type(4)));

__device__ __forceinline__ unsigned short f2bf_rne(float f) {
    unsigned int u = __float_as_uint(f);
    u += 0x7fffu + ((u >> 16) & 1u);
    return (unsigned short)(u >> 16);
}

union BfPack { bf16x8 v; unsigned short s[8]; };

// Load 8 consecutive fp32 and round-to-nearest-even into a bf16x8 fragment slice.
__device__ __forceinline__ bf16x8 load_row_bf16(const float* __restrict__ p) {
    const float4* p4 = (const float4*)p;
    float4 a = p4[0], b = p4[1];
    BfPack u;
    u.s[0] = f2bf_rne(a.x); u.s[1] = f2bf_rne(a.y);
    u.s[2] = f2bf_rne(a.z); u.s[3] = f2bf_rne(a.w);
    u.s[4] = f2bf_rne(b.x); u.s[5] = f2bf_rne(b.y);
    u.s[6] = f2bf_rne(b.z); u.s[7] = f2bf_rne(b.w);
    return u.v;
}

// ---------------------------------------------------------------------------
// Kernel 1: transpose W (fp32 [c][o]) -> Wt (bf16 [o][c]).
// wt row o, cols c: serves as the A-operand (W^T) of the swapped MFMA.
__global__ void wt_kernel(const float* __restrict__ Wq,
                          const float* __restrict__ Wk,
                          const float* __restrict__ Wv,
                          unsigned short* __restrict__ wt) {
    int t = threadIdx.x;  // 256 threads, 1 block
    for (int w = 0; w < 3; ++w) {
        const float* W = (w == 0) ? Wq : (w == 1) ? Wk : Wv;
        for (int i = t; i < 4096; i += 256) {
            int o = i >> 6, c = i & 63;
            wt[w * 4096 + i] = f2bf_rne(W[c * 64 + o]);
        }
    }
}

// ---------------------------------------------------------------------------
// Kernel 2: q/k projection (MFMA, SWAPPED operands -> D[row=channel][col=edge])
// Wave = 16 edges. Lane (m = lane&15, quad = lane>>4) accumulates channels
// quad*4..+3 of edge m for each head; d-reduction = 4 in-lane FMAs + 2
// shfl_xor (quad bits). Lane (m,quad) then owns (edge m, head quad):
// coalesced score store + segmented max-scan + tail-only atomicMax.
__global__ __launch_bounds__(256) void score_kernel(
    const float* __restrict__ query, const float* __restrict__ key,
    const float* __restrict__ bq, const float* __restrict__ bk,
    const int* __restrict__ index,
    const unsigned short* __restrict__ wt,
    float* __restrict__ score, int* __restrict__ smax) {
    int lane = threadIdx.x & 63;
    int wid  = threadIdx.x >> 6;
    int e0   = blockIdx.x * 64 + wid * 16;
    int m    = lane & 15, quad = lane >> 4;

    int n = index[e0 + m];   // identical across the 4 quad groups

    const float* qrow = query + (size_t)(e0 + m) * 64 + quad * 8;
    const float* krow = key   + (size_t)(e0 + m) * 64 + quad * 8;
    bf16x8 aq0 = load_row_bf16(qrow);
    bf16x8 aq1 = load_row_bf16(qrow + 32);
    bf16x8 ak0 = load_row_bf16(krow);
    bf16x8 ak1 = load_row_bf16(krow + 32);

    const bf16x8* wq8 = (const bf16x8*)(wt);
    const bf16x8* wk8 = (const bf16x8*)(wt + 4096);
    const f32x4* bq4p = (const f32x4*)bq;
    const f32x4* bk4p = (const f32x4*)bk;

    float s_mine = 0.f;

    #pragma unroll
    for (int h = 0; h < H_N; ++h) {
        int bi0 = (h * 16 + m) * 8 + quad;      // k-slice s=0
        int bi1 = bi0 + 4;                      // k-slice s=1
        f32x4 cq = {0.f, 0.f, 0.f, 0.f}, ck = {0.f, 0.f, 0.f, 0.f};
        // A = W^T (16 chan x 64), B = X^T (64 x 16 edges) -> D[chan][edge]
        cq = __builtin_amdgcn_mfma_f32_16x16x32_bf16(wq8[bi0], aq0, cq, 0, 0, 0);
        cq = __builtin_amdgcn_mfma_f32_16x16x32_bf16(wq8[bi1], aq1, cq, 0, 0, 0);
        ck = __builtin_amdgcn_mfma_f32_16x16x32_bf16(wk8[bi0], ak0, ck, 0, 0, 0);
        ck = __builtin_amdgcn_mfma_f32_16x16x32_bf16(wk8[bi1], ak1, ck, 0, 0, 0);
        f32x4 bqv = bq4p[h * 4 + quad];   // bias for channels quad*4..+3
        f32x4 bkv = bk4p[h * 4 + quad];
        float p = 0.f;
        #pragma unroll
        for (int r = 0; r < 4; ++r)
            p += (cq[r] + bqv[r]) * (ck[r] + bkv[r]);
        // sum the 16 head-channels: 4 in-lane + butterfly over lane bits 4,5
        p += __shfl_xor(p, 16, 64);
        p += __shfl_xor(p, 32, 64);
        if (h == quad) s_mine = p * 0.25f;   // / sqrt(D=16)
    }

    // coalesced 256B store: score[e][h] with lane (m,quad) -> slot m*4+quad
    score[(size_t)e0 * 4 + m * 4 + quad] = s_mine;

    // segmented inclusive max-scan over edges m within each quad group
    float s = s_mine;
    #pragma unroll
    for (int d = 1; d <= 8; d <<= 1) {
        float up = __shfl_up(s, d, 64);
        int  nup = __shfl_up(n, d, 64);
        if (m >= d && nup == n) s = fmaxf(s, up);
    }
    int ndn = __shfl_down(n, 1, 64);        // tail test without index[e+1] load
    bool tail = (m == 15) || (ndn != n);
    if (tail && s > 0.f)
        atomicMax(smax + n * 4 + quad, __float_as_int(s));
}

// ---------------------------------------------------------------------------
// Kernel 3: denom[n,h] += segment-sum of exp(score - smax).
// 64 edges per wave (4x fewer waves), float4/int4 gathers, shfl_down tails.
__global__ __launch_bounds__(256) void expsum_kernel(
    const float* __restrict__ score, const int* __restrict__ index,
    const int* __restrict__ smax, float* __restrict__ denom) {
    int lane = threadIdx.x & 63;
    int wid  = threadIdx.x >> 6;
    int e    = blockIdx.x * 256 + wid * 64 + lane;   // one edge per lane

    int n = index[e];
    i32x4 sm = ((const i32x4*)smax)[n];              // broadcast within segment
    f32x4 sc = ((const f32x4*)score)[e];             // coalesced 1KB/wave
    float ex[4];
    #pragma unroll
    for (int h = 0; h < 4; ++h)
        ex[h] = __expf(sc[h] - __int_as_float(sm[h]));

    #pragma unroll
    for (int d = 1; d <= 32; d <<= 1) {
        int nup = __shfl_up(n, d, 64);
        bool ok = (lane >= d) && (nup == n);
        #pragma unroll
        for (int h = 0; h < 4; ++h) {
            float up = __shfl_up(ex[h], d, 64);
            if (ok) ex[h] += up;
        }
    }
    int ndn = __shfl_down(n, 1, 64);
    bool tail = (lane == 63) || (ndn != n);
    if (tail) {
        #pragma unroll
        for (int h = 0; h < 4; ++h)
            atomicAdd(denom + n * 4 + h, ex[h]);
    }
}

// ---------------------------------------------------------------------------
// Kernel 4: nd[n,h] = {smax, 1/(denom + exp(-smax))}
__global__ void finalize_kernel(const int* __restrict__ smax,
                                const float* __restrict__ denom,
                                float2* __restrict__ nd) {
    int i = blockIdx.x * 256 + threadIdx.x;
    if (i < NODES * H_N) {
        float sm = __int_as_float(smax[i]);
        float d  = denom[i] + __expf(-sm);
        nd[i] = make_float2(sm, 1.f / d);
    }
}

// ---------------------------------------------------------------------------
// Kernel 5: v projection (swapped MFMA), scale by attn, float4 stores.
__global__ __launch_bounds__(256) void out_kernel(
    const float* __restrict__ value, const float* __restrict__ bv,
    const int* __restrict__ index, const unsigned short* __restrict__ wt,
    const float* __restrict__ score, const float2* __restrict__ nd,
    float* __restrict__ out) {
    int lane = threadIdx.x & 63;
    int wid  = threadIdx.x >> 6;
    int e0   = blockIdx.x * 64 + wid * 16;
    int m    = lane & 15, quad = lane >> 4;

    // lane (m,quad) owns (edge m, head quad)
    int n  = index[e0 + m];
    float2 t = nd[n * 4 + quad];
    float attn = __expf(score[(size_t)e0 * 4 + m * 4 + quad] - t.x) * t.y;

    const float* vrow = value + (size_t)(e0 + m) * 64 + quad * 8;
    bf16x8 av0 = load_row_bf16(vrow);
    bf16x8 av1 = load_row_bf16(vrow + 32);
    const bf16x8* wv8 = (const bf16x8*)(wt + 8192);
    const f32x4* bv4p = (const f32x4*)bv;

    #pragma unroll
    for (int h = 0; h < H_N; ++h) {
        int bi0 = (h * 16 + m) * 8 + quad;
        f32x4 cv = {0.f, 0.f, 0.f, 0.f};
        cv = __builtin_amdgcn_mfma_f32_16x16x32_bf16(wv8[bi0], av0, cv, 0, 0, 0);
        cv = __builtin_amdgcn_mfma_f32_16x16x32_bf16(wv8[bi0 + 4], av1, cv, 0, 0, 0);
        f32x4 bvv = bv4p[h * 4 + quad];
        // attn(edge m, head h) lives in lane h*16+m
        float a = __shfl(attn, (h << 4) | m, 64);
        f32x4 o;
        #pragma unroll
        for (int r = 0; r < 4; ++r) o[r] = (cv[r] + bvv[r]) * a;
        // lane holds channels h*16+quad*4..+3 of edge m: coalesced float4 store
        *(f32x4*)(out + (size_t)(e0 + m) * 64 + h * 16 + quad * 4) = o;
    }
}

// ---------------------------------------------------------------------------
extern "C" void kernel_launch(void* const* d_in, const int* in_sizes, int n_in,
                              void* d_out, int out_size, void* d_ws, size_t ws_size,
                              hipStream_t stream) {
    const float* query = (const float*)d_in[0];
    const float* key   = (const float*)d_in[1];
    const float* value = (const float*)d_in[2];
    const float* Wq    = (const float*)d_in[3];
    const float* bq    = (const float*)d_in[4];
    const float* Wk    = (const float*)d_in[5];
    const float* bk    = (const float*)d_in[6];
    const float* Wv    = (const float*)d_in[7];
    const float* bv    = (const float*)d_in[8];
    const int*   index = (const int*)d_in[9];

    // workspace layout
    char* ws = (char*)d_ws;
    unsigned short* wt = (unsigned short*)ws;                         // 24576 B (pad 32768)
    float* score = (float*)(ws + 32768);                              // E*4*4 = 12.8 MB
    char*  p2    = ws + 32768 + (size_t)E_N * 16;
    int*   smax  = (int*)p2;                                          // N*4*4
    float* denom = (float*)(p2 + (size_t)NODES * 16);                 // N*4*4
    float2* nd   = (float2*)(p2 + 2 * (size_t)NODES * 16);            // N*4*8

    // smax = 0.0f (clamp floor), denom = 0.0f — contiguous, one memset
    hipMemsetAsync(smax, 0, 2 * (size_t)NODES * 16, stream);
    wt_kernel<<<1, 256, 0, stream>>>(Wq, Wk, Wv, wt);
    score_kernel<<<E_N / 64, 256, 0, stream>>>(query, key, bq, bk, index, wt,
                                               score, smax);
    expsum_kernel<<<E_N / 256, 256, 0, stream>>>(score, index, smax, denom);
    finalize_kernel<<<(NODES * H_N + 255) / 256, 256, 0, stream>>>(smax, denom, nd);
    out_kernel<<<E_N / 64, 256, 0, stream>>>(value, bv, index, wt, score, nd,
                                             (float*)d_out);
}

// Round 2
// 651.336 us; speedup vs baseline: 1.0436x; 1.0436x over previous
//
#include <hip/hip_runtime.h>
#include <hip/hip_bf16.h>
#include <math.h>

// Problem constants (fixed by the reference)
#define E_N 800000
#define C_N 64
#define H_N 4
#define D_N 16
#define NODES 50000

typedef __bf16 bf16x8 __attribute__((ext_vector_type(8)));
typedef float f32x4 __attribute__((ext_vector_type(4)));
typedef int i32x4 __attribute__((ext_vector_type(4)));

__device__ __forceinline__ unsigned short f2bf_rne(float f) {
    unsigned int u = __float_as_uint(f);
    u += 0x7fffu + ((u >> 16) & 1u);
    return (unsigned short)(u >> 16);
}

union BfPack { bf16x8 v; unsigned short s[8]; };

// Load 8 consecutive fp32 (non-temporal: streaming, read-once) and
// round-to-nearest-even into a bf16x8 fragment slice.
__device__ __forceinline__ bf16x8 load_row_bf16_nt(const float* __restrict__ p) {
    const f32x4* p4 = (const f32x4*)p;
    f32x4 a = __builtin_nontemporal_load(p4);
    f32x4 b = __builtin_nontemporal_load(p4 + 1);
    BfPack u;
    u.s[0] = f2bf_rne(a[0]); u.s[1] = f2bf_rne(a[1]);
    u.s[2] = f2bf_rne(a[2]); u.s[3] = f2bf_rne(a[3]);
    u.s[4] = f2bf_rne(b[0]); u.s[5] = f2bf_rne(b[1]);
    u.s[6] = f2bf_rne(b[2]); u.s[7] = f2bf_rne(b[3]);
    return u.v;
}

// ---------------------------------------------------------------------------
// Kernel 1: transpose W (fp32 [c][o]) -> Wt (bf16 [o][c]).
// wt row o, cols c: serves as the A-operand (W^T) of the swapped MFMA.
__global__ void wt_kernel(const float* __restrict__ Wq,
                          const float* __restrict__ Wk,
                          const float* __restrict__ Wv,
                          unsigned short* __restrict__ wt) {
    int t = threadIdx.x;  // 256 threads, 1 block
    for (int w = 0; w < 3; ++w) {
        const float* W = (w == 0) ? Wq : (w == 1) ? Wk : Wv;
        for (int i = t; i < 4096; i += 256) {
            int o = i >> 6, c = i & 63;
            wt[w * 4096 + i] = f2bf_rne(W[c * 64 + o]);
        }
    }
}

// ---------------------------------------------------------------------------
// Kernel 2: q/k projection (MFMA, swapped operands -> D[row=channel][col=edge])
// Wave = 64 edges = 4 groups of 16 (latency hiding: 32 independent global
// loads in flight per wave; weight fragments loaded once per head, reused
// across the 4 groups). Lane (m = lane&15, quad = lane>>4) owns
// (edge g*16+m, head quad) after the 2-shuffle quad butterfly.
__global__ __launch_bounds__(256) void score_kernel(
    const float* __restrict__ query, const float* __restrict__ key,
    const float* __restrict__ bq, const float* __restrict__ bk,
    const int* __restrict__ index,
    const unsigned short* __restrict__ wt,
    float* __restrict__ score, int* __restrict__ smax) {
    int lane = threadIdx.x & 63;
    int wid  = threadIdx.x >> 6;
    int e0   = blockIdx.x * 256 + wid * 64;   // 64 edges per wave
    int m    = lane & 15, quad = lane >> 4;

    // inputs for 4 groups of 16 edges: 32 independent 16B loads issued early
    bf16x8 aq0[4], aq1[4], ak0[4], ak1[4];
    int n[4];
    #pragma unroll
    for (int g = 0; g < 4; ++g) {
        const float* qrow = query + (size_t)(e0 + g * 16 + m) * 64 + quad * 8;
        const float* krow = key   + (size_t)(e0 + g * 16 + m) * 64 + quad * 8;
        aq0[g] = load_row_bf16_nt(qrow);
        aq1[g] = load_row_bf16_nt(qrow + 32);
        ak0[g] = load_row_bf16_nt(krow);
        ak1[g] = load_row_bf16_nt(krow + 32);
        n[g]   = index[e0 + g * 16 + m];
    }

    const bf16x8* wq8 = (const bf16x8*)(wt);
    const bf16x8* wk8 = (const bf16x8*)(wt + 4096);
    const f32x4* bq4p = (const f32x4*)bq;
    const f32x4* bk4p = (const f32x4*)bk;

    float s_mine[4];

    #pragma unroll
    for (int h = 0; h < H_N; ++h) {
        int bi0 = (h * 16 + m) * 8 + quad;      // k-slice s=0
        int bi1 = bi0 + 4;                      // k-slice s=1
        bf16x8 wq0 = wq8[bi0], wq1 = wq8[bi1];
        bf16x8 wk0 = wk8[bi0], wk1 = wk8[bi1];
        f32x4 bqv = bq4p[h * 4 + quad];   // bias for channels quad*4..+3
        f32x4 bkv = bk4p[h * 4 + quad];
        #pragma unroll
        for (int g = 0; g < 4; ++g) {
            f32x4 cq = {0.f, 0.f, 0.f, 0.f}, ck = {0.f, 0.f, 0.f, 0.f};
            // A = W^T (16 chan x 64), B = X^T (64 x 16 edges) -> D[chan][edge]
            cq = __builtin_amdgcn_mfma_f32_16x16x32_bf16(wq0, aq0[g], cq, 0, 0, 0);
            cq = __builtin_amdgcn_mfma_f32_16x16x32_bf16(wq1, aq1[g], cq, 0, 0, 0);
            ck = __builtin_amdgcn_mfma_f32_16x16x32_bf16(wk0, ak0[g], ck, 0, 0, 0);
            ck = __builtin_amdgcn_mfma_f32_16x16x32_bf16(wk1, ak1[g], ck, 0, 0, 0);
            float p = 0.f;
            #pragma unroll
            for (int r = 0; r < 4; ++r)
                p += (cq[r] + bqv[r]) * (ck[r] + bkv[r]);
            // sum the 16 head-channels: 4 in-lane + butterfly over lane bits 4,5
            p += __shfl_xor(p, 16, 64);
            p += __shfl_xor(p, 32, 64);
            if (h == quad) s_mine[g] = p * 0.25f;   // / sqrt(D=16)
        }
    }

    // coalesced stores: score[e][h] with lane (m,quad) -> slot m*4+quad
    #pragma unroll
    for (int g = 0; g < 4; ++g)
        score[(size_t)(e0 + g * 16) * 4 + m * 4 + quad] = s_mine[g];

    // segmented inclusive max-scan over edges m within each quad group;
    // 4 groups interleaved so the serial DS-latency chains overlap
    float s[4];
    #pragma unroll
    for (int g = 0; g < 4; ++g) s[g] = s_mine[g];
    #pragma unroll
    for (int d = 1; d <= 8; d <<= 1) {
        #pragma unroll
        for (int g = 0; g < 4; ++g) {
            float up = __shfl_up(s[g], d, 64);
            int  nup = __shfl_up(n[g], d, 64);
            if (m >= d && nup == n[g]) s[g] = fmaxf(s[g], up);
        }
    }
    #pragma unroll
    for (int g = 0; g < 4; ++g) {
        int ndn = __shfl_down(n[g], 1, 64);
        bool tail = (m == 15) || (ndn != n[g]);
        if (tail && s[g] > 0.f)
            atomicMax(smax + n[g] * 4 + quad, __float_as_int(s[g]));
    }
}

// ---------------------------------------------------------------------------
// Kernel 3: denom[n,h] += segment-sum of exp(score - smax).
// 64 edges per wave, float4/int4 gathers, shfl_down tails.
__global__ __launch_bounds__(256) void expsum_kernel(
    const float* __restrict__ score, const int* __restrict__ index,
    const int* __restrict__ smax, float* __restrict__ denom) {
    int lane = threadIdx.x & 63;
    int wid  = threadIdx.x >> 6;
    int e    = blockIdx.x * 256 + wid * 64 + lane;   // one edge per lane

    int n = index[e];
    i32x4 sm = ((const i32x4*)smax)[n];              // broadcast within segment
    f32x4 sc = ((const f32x4*)score)[e];             // coalesced 1KB/wave
    float ex[4];
    #pragma unroll
    for (int h = 0; h < 4; ++h)
        ex[h] = __expf(sc[h] - __int_as_float(sm[h]));

    #pragma unroll
    for (int d = 1; d <= 32; d <<= 1) {
        int nup = __shfl_up(n, d, 64);
        bool ok = (lane >= d) && (nup == n);
        #pragma unroll
        for (int h = 0; h < 4; ++h) {
            float up = __shfl_up(ex[h], d, 64);
            if (ok) ex[h] += up;
        }
    }
    int ndn = __shfl_down(n, 1, 64);
    bool tail = (lane == 63) || (ndn != n);
    if (tail) {
        #pragma unroll
        for (int h = 0; h < 4; ++h)
            atomicAdd(denom + n * 4 + h, ex[h]);
    }
}

// ---------------------------------------------------------------------------
// Kernel 4: nd[n,h] = {smax, 1/(denom + exp(-smax))}
__global__ void finalize_kernel(const int* __restrict__ smax,
                                const float* __restrict__ denom,
                                float2* __restrict__ nd) {
    int i = blockIdx.x * 256 + threadIdx.x;
    if (i < NODES * H_N) {
        float sm = __int_as_float(smax[i]);
        float d  = denom[i] + __expf(-sm);
        nd[i] = make_float2(sm, 1.f / d);
    }
}

// ---------------------------------------------------------------------------
// Kernel 5: v projection (swapped MFMA), scale by attn, float4 NT stores.
// 64 edges per wave (4 groups), weights amortized across groups.
__global__ __launch_bounds__(256) void out_kernel(
    const float* __restrict__ value, const float* __restrict__ bv,
    const int* __restrict__ index, const unsigned short* __restrict__ wt,
    const float* __restrict__ score, const float2* __restrict__ nd,
    float* __restrict__ out) {
    int lane = threadIdx.x & 63;
    int wid  = threadIdx.x >> 6;
    int e0   = blockIdx.x * 256 + wid * 64;   // 64 edges per wave
    int m    = lane & 15, quad = lane >> 4;

    // per-group attn: lane (m,quad) owns (edge g*16+m, head quad);
    // independent index->nd gather chains overlap across the 4 groups
    int n[4]; float2 t[4]; float sc[4];
    #pragma unroll
    for (int g = 0; g < 4; ++g) n[g] = index[e0 + g * 16 + m];
    #pragma unroll
    for (int g = 0; g < 4; ++g) t[g] = nd[n[g] * 4 + quad];
    #pragma unroll
    for (int g = 0; g < 4; ++g)
        sc[g] = score[(size_t)(e0 + g * 16) * 4 + m * 4 + quad];
    float attn[4];
    #pragma unroll
    for (int g = 0; g < 4; ++g)
        attn[g] = __expf(sc[g] - t[g].x) * t[g].y;

    bf16x8 av0[4], av1[4];
    #pragma unroll
    for (int g = 0; g < 4; ++g) {
        const float* vrow = value + (size_t)(e0 + g * 16 + m) * 64 + quad * 8;
        av0[g] = load_row_bf16_nt(vrow);
        av1[g] = load_row_bf16_nt(vrow + 32);
    }
    const bf16x8* wv8 = (const bf16x8*)(wt + 8192);
    const f32x4* bv4p = (const f32x4*)bv;

    #pragma unroll
    for (int h = 0; h < H_N; ++h) {
        int bi0 = (h * 16 + m) * 8 + quad;
        bf16x8 wv0 = wv8[bi0], wv1 = wv8[bi0 + 4];
        f32x4 bvv = bv4p[h * 4 + quad];
        #pragma unroll
        for (int g = 0; g < 4; ++g) {
            f32x4 cv = {0.f, 0.f, 0.f, 0.f};
            cv = __builtin_amdgcn_mfma_f32_16x16x32_bf16(wv0, av0[g], cv, 0, 0, 0);
            cv = __builtin_amdgcn_mfma_f32_16x16x32_bf16(wv1, av1[g], cv, 0, 0, 0);
            // attn(edge m, head h) lives in lane h*16+m
            float a = __shfl(attn[g], (h << 4) | m, 64);
            f32x4 o;
            #pragma unroll
            for (int r = 0; r < 4; ++r) o[r] = (cv[r] + bvv[r]) * a;
            // lane holds channels h*16+quad*4..+3 of edge g*16+m
            __builtin_nontemporal_store(
                o, (f32x4*)(out + (size_t)(e0 + g * 16 + m) * 64 + h * 16 + quad * 4));
        }
    }
}

// ---------------------------------------------------------------------------
extern "C" void kernel_launch(void* const* d_in, const int* in_sizes, int n_in,
                              void* d_out, int out_size, void* d_ws, size_t ws_size,
                              hipStream_t stream) {
    const float* query = (const float*)d_in[0];
    const float* key   = (const float*)d_in[1];
    const float* value = (const float*)d_in[2];
    const float* Wq    = (const float*)d_in[3];
    const float* bq    = (const float*)d_in[4];
    const float* Wk    = (const float*)d_in[5];
    const float* bk    = (const float*)d_in[6];
    const float* Wv    = (const float*)d_in[7];
    const float* bv    = (const float*)d_in[8];
    const int*   index = (const int*)d_in[9];

    // workspace layout
    char* ws = (char*)d_ws;
    unsigned short* wt = (unsigned short*)ws;                         // 24576 B (pad 32768)
    float* score = (float*)(ws + 32768);                              // E*4*4 = 12.8 MB
    char*  p2    = ws + 32768 + (size_t)E_N * 16;
    int*   smax  = (int*)p2;                                          // N*4*4
    float* denom = (float*)(p2 + (size_t)NODES * 16);                 // N*4*4
    float2* nd   = (float2*)(p2 + 2 * (size_t)NODES * 16);            // N*4*8

    // smax = 0.0f (clamp floor), denom = 0.0f — contiguous, one memset
    hipMemsetAsync(smax, 0, 2 * (size_t)NODES * 16, stream);
    wt_kernel<<<1, 256, 0, stream>>>(Wq, Wk, Wv, wt);
    score_kernel<<<E_N / 256, 256, 0, stream>>>(query, key, bq, bk, index, wt,
                                                score, smax);
    expsum_kernel<<<E_N / 256, 256, 0, stream>>>(score, index, smax, denom);
    finalize_kernel<<<(NODES * H_N + 255) / 256, 256, 0, stream>>>(smax, denom, nd);
    out_kernel<<<E_N / 256, 256, 0, stream>>>(value, bv, index, wt, score, nd,
                                              (float*)d_out);
}